// Round 7
// baseline (187.261 us; speedup 1.0000x reference)
//
#include <hip/hip_runtime.h>

#define KCODES 512
#define DDIM   64
#define NPIX   1024                      // 32*32 spatial per batch
#define QELEMS (64 * DDIM * NPIX)        // 4194304
// Ref-vs-true reorder bound: 2 roundings at ulp(~64) per dist (7.6e-6+3.8e-6... 
// pairwise <=1.64e-5) + fma-path noise <=1e-6. Flag at 2e-5 (>10x slack).
#define FLAG_GAP 2e-5f

// Main pass: fp32 fmaf scan of s_k = w2_k - 2*dot_k (x2 constant, dropped) ->
// candidate + second-best. Pixels with gap < FLAG_GAP are re-resolved with the
// BIT-EXACT numpy fp32 emulation proven in R3 (seq d, separate mul+add,
// dist = (x2 - 2dot) + w2, strict-< first-min). w2/x2 always numpy-exact.
__global__ __launch_bounds__(256, 4) void vq_kernel(
    const float* __restrict__ x, const float* __restrict__ w,
    float* __restrict__ qout, float* __restrict__ aout) {
#pragma clang fp contract(off)

  __shared__ float  xs[DDIM][64];        // 16 KB x tile (fixup use)
  __shared__ float  sx2[64];             // numpy-exact x2 per pixel
  __shared__ float  w2f[KCODES];         // 2 KB numpy-exact ||w_k||^2
  __shared__ float  sm1[4][64], sm2[4][64];
  __shared__ int    si1[4][64];
  __shared__ int    skm[64];
  __shared__ unsigned long long s_fmask;
  __shared__ float  rv[256];
  __shared__ int    ri[256];

  const int tid  = threadIdx.x;
  const int lane = tid & 63;
  const int wid  = __builtin_amdgcn_readfirstlane(tid >> 6);  // wave id, uniform
  const int b    = blockIdx.x >> 4;
  const int n0   = (blockIdx.x & 15) << 6;
  const size_t pixbase = (size_t)blockIdx.x << 6;

  // ---- w2 in fp32, sequential over d (numpy order), per block ----
#pragma unroll
  for (int kk = 0; kk < 2; ++kk) {
    int k = tid + kk * 256;
    float s = 0.0f;
    for (int d = 0; d < DDIM; ++d) {
      float v = w[d * KCODES + k];
      float p = v * v;                   // rounded product
      s = s + p;                         // rounded add, d ascending
    }
    w2f[k] = s;
  }

  // ---- x column into registers (coalesced; static indices only) ----
  float xr[DDIM];
  {
    const float* xp = x + (size_t)b * (DDIM * NPIX) + n0 + lane;
#pragma unroll
    for (int d = 0; d < DDIM; ++d) xr[d] = xp[(size_t)d * NPIX];
  }

  // ---- numpy-exact x2 (seq d, mul+add); stage xs for fixup ----
  float x2 = 0.0f;
#pragma unroll
  for (int d = 0; d < DDIM; ++d) {
    float p = xr[d] * xr[d];
    x2 = x2 + p;
  }
#pragma unroll
  for (int dd = 0; dd < 16; ++dd) {      // wave wid stages 16 d-rows
    int d = wid * 16 + dd;
    xs[d][lane] = xr[d];
  }
  if (tid < 64) sx2[lane] = x2;
  __syncthreads();

  // ---- fma main scan: wave `wid` owns k in [wid*128, wid*128+128) ----
  float m1 = 3.4e38f, m2 = 3.4e38f;
  int   i1 = 0;
  const int kbase = wid * 128;

#pragma unroll 1
  for (int kt = 0; kt < 8; ++kt) {
    const int k0 = kbase + kt * 16;
    float acc[16];
#pragma unroll
    for (int j = 0; j < 16; ++j) acc[j] = 0.f;

#pragma unroll
    for (int d = 0; d < DDIM; ++d) {
      // wave-uniform address -> scalar s_load feed (R3-proven, SGPR operands)
      const float4* wr = reinterpret_cast<const float4*>(w + d * KCODES + k0);
      float4 w0 = wr[0];
      float4 w1 = wr[1];
      float4 w2v = wr[2];
      float4 w3 = wr[3];
      float xv = xr[d];
      acc[0]  = fmaf(xv, w0.x,  acc[0]);
      acc[1]  = fmaf(xv, w0.y,  acc[1]);
      acc[2]  = fmaf(xv, w0.z,  acc[2]);
      acc[3]  = fmaf(xv, w0.w,  acc[3]);
      acc[4]  = fmaf(xv, w1.x,  acc[4]);
      acc[5]  = fmaf(xv, w1.y,  acc[5]);
      acc[6]  = fmaf(xv, w1.z,  acc[6]);
      acc[7]  = fmaf(xv, w1.w,  acc[7]);
      acc[8]  = fmaf(xv, w2v.x, acc[8]);
      acc[9]  = fmaf(xv, w2v.y, acc[9]);
      acc[10] = fmaf(xv, w2v.z, acc[10]);
      acc[11] = fmaf(xv, w2v.w, acc[11]);
      acc[12] = fmaf(xv, w3.x,  acc[12]);
      acc[13] = fmaf(xv, w3.y,  acc[13]);
      acc[14] = fmaf(xv, w3.z,  acc[14]);
      acc[15] = fmaf(xv, w3.w,  acc[15]);
    }

#pragma unroll
    for (int j = 0; j < 16; ++j) {
      float s = fmaf(-2.0f, acc[j], w2f[k0 + j]);
      bool lt = s < m1;
      float om1 = m1;
      m2 = lt ? om1 : fminf(s, m2);
      m1 = lt ? s : m1;
      i1 = lt ? (k0 + j) : i1;
    }
  }

  sm1[wid][lane] = m1;
  sm2[wid][lane] = m2;
  si1[wid][lane] = i1;
  __syncthreads();

  // ---- merge 4 waves; flag near-ties via ballot (wave 0) ----
  if (tid < 64) {
    float M1 = sm1[0][lane], M2 = sm2[0][lane];
    int   I1 = si1[0][lane];
#pragma unroll
    for (int c = 1; c < 4; ++c) {
      float c1 = sm1[c][lane];
      if (c1 < M1) { M2 = fminf(M1, sm2[c][lane]); M1 = c1; I1 = si1[c][lane]; }
      else         { M2 = fminf(M2, c1); }
    }
    skm[lane] = I1;
    unsigned long long bal = __ballot(M2 - M1 < FLAG_GAP);
    if (lane == 0) s_fmask = bal;
  }
  __syncthreads();

  // ---- exact numpy-emulation fixup for flagged pixels (block-cooperative) ----
  unsigned long long fm = s_fmask;
  while (fm) {
    const int L = __builtin_ctzll(fm);
    fm &= (fm - 1);
    const float x2L = sx2[L];
    float bv = 3.4e38f;
    int   bi = 0;
#pragma unroll
    for (int kk = 0; kk < 2; ++kk) {
      int k = tid + kk * 256;            // ascending: strict < keeps lowest k
      float dot = 0.0f;
      for (int d = 0; d < DDIM; ++d) {
        float p = xs[d][L] * w[d * KCODES + k];   // rounded product
        dot = dot + p;                            // rounded add, d ascending
      }
      float t  = x2L - 2.0f * dot;       // rounds at ulp(~64) — the ref's grid
      float s2 = t + w2f[k];             // rounds
      if (s2 < bv) { bv = s2; bi = k; }
    }
    rv[tid] = bv;
    ri[tid] = bi;
    __syncthreads();
    for (int off = 128; off > 0; off >>= 1) {
      if (tid < off) {
        float ov = rv[tid + off];
        int   oi = ri[tid + off];
        if (ov < rv[tid] || (ov == rv[tid] && oi < ri[tid])) {
          rv[tid] = ov;
          ri[tid] = oi;
        }
      }
      __syncthreads();
    }
    if (tid == 0) skm[L] = ri[0];
    __syncthreads();
  }

  // ---- outputs ----
  if (tid < 64) aout[pixbase + lane] = (float)skm[lane];

  const int kmin = skm[lane];
  float* qp = qout + (size_t)b * (DDIM * NPIX) + n0 + lane;
#pragma unroll
  for (int dd = 0; dd < 16; ++dd) {
    int d = wid * 16 + dd;
    qp[(size_t)d * NPIX] = w[d * KCODES + kmin];
  }
}

extern "C" void kernel_launch(void* const* d_in, const int* in_sizes, int n_in,
                              void* d_out, int out_size, void* d_ws, size_t ws_size,
                              hipStream_t stream) {
  const float* x = (const float*)d_in[0];
  const float* w = (const float*)d_in[1];
  float* qout = (float*)d_out;
  float* aout = (float*)d_out + QELEMS;

  vq_kernel<<<64 * 16, 256, 0, stream>>>(x, w, qout, aout);
}

// Round 8
// 109.439 us; speedup vs baseline: 1.7111x; 1.7111x over previous
//
#include <hip/hip_runtime.h>

#define KCODES 512
#define DDIM   64
#define NPIX   1024                      // 32*32 spatial per batch
#define QELEMS (64 * DDIM * NPIX)        // 4194304
// Reorder bound between fma-scan order and numpy-ref order:
// dist = fl(fl(x2-2dot)+w2): 2 roundings <= ulp(x2~<128)/2 * 2 = 1.53e-5 per
// dist, 3.05e-5 per pair, + fma-vs-mul/add dot noise ~2e-6. Flag at 4e-5.
#define FLAG_GAP 4e-5f

// Main scan: fmaf over s_k = w2_k - 2*dot_k (x2 constant, dropped), top-2
// tracked. Near-ties re-resolved with the BIT-EXACT numpy fp32 emulation
// (R3/R7-proven: seq d, separate mul+add, dist=(x2-2dot)+w2, strict-< min).
// Structure = R3's proven codegen shape: x in LDS, wave-uniform scalar w feed,
// no big per-thread arrays (R7's xr[64] spilled to scratch under bounds(,4)).
__global__ __launch_bounds__(256) void vq_kernel(
    const float* __restrict__ x, const float* __restrict__ w,
    float* __restrict__ qout, float* __restrict__ aout) {
#pragma clang fp contract(off)

  __shared__ float  xs[DDIM][64];        // 16 KB x tile [d][pixel]
  __shared__ float  sx2[64];             // numpy-exact x2 per pixel
  __shared__ float  w2f[KCODES];         // 2 KB numpy-exact ||w_k||^2
  __shared__ float  sm1[4][64], sm2[4][64];
  __shared__ int    si1[4][64];
  __shared__ int    skm[64];
  __shared__ unsigned long long s_fmask;
  __shared__ float  rv[256];
  __shared__ int    ri[256];

  const int tid  = threadIdx.x;
  const int lane = tid & 63;
  const int wid  = __builtin_amdgcn_readfirstlane(tid >> 6);  // wave id, uniform
  const int b    = blockIdx.x >> 4;
  const int n0   = (blockIdx.x & 15) << 6;
  const size_t pixbase = (size_t)blockIdx.x << 6;

  // ---- stage x tile into LDS (coalesced 64-lane rows) ----
  {
    const float* xp = x + (size_t)b * (DDIM * NPIX) + n0;
#pragma unroll
    for (int dd = 0; dd < 16; ++dd) {
      int d = dd * 4 + wid;
      xs[d][lane] = xp[(size_t)d * NPIX + lane];
    }
  }

  // ---- w2 in fp32, sequential over d (numpy order), per block ----
#pragma unroll
  for (int kk = 0; kk < 2; ++kk) {
    int k = tid + kk * 256;
    float s = 0.0f;
    for (int d = 0; d < DDIM; ++d) {
      float v = w[d * KCODES + k];
      float p = v * v;                   // rounded product
      s = s + p;                         // rounded add, d ascending
    }
    w2f[k] = s;
  }
  __syncthreads();

  // ---- numpy-exact x2 per pixel (seq d, mul+add), wave 0 publishes ----
  {
    float x2 = 0.0f;
#pragma unroll
    for (int d = 0; d < DDIM; ++d) {
      float xv = xs[d][lane];
      float p = xv * xv;
      x2 = x2 + p;
    }
    if (tid < 64) sx2[lane] = x2;
  }

  // ---- fma main scan: wave `wid` owns k in [wid*128, wid*128+128) ----
  float m1 = 3.4e38f, m2 = 3.4e38f;
  int   i1 = 0;
  const int kbase = wid * 128;

#pragma unroll 1
  for (int kt = 0; kt < 8; ++kt) {
    const int k0 = kbase + kt * 16;
    float acc[16];
#pragma unroll
    for (int j = 0; j < 16; ++j) acc[j] = 0.f;

#pragma unroll
    for (int d = 0; d < DDIM; ++d) {
      // wave-uniform address -> scalar s_load feed (R3-proven)
      const float4* wr = reinterpret_cast<const float4*>(w + d * KCODES + k0);
      float4 w0 = wr[0];
      float4 w1 = wr[1];
      float4 w2v = wr[2];
      float4 w3 = wr[3];
      float xv = xs[d][lane];
      acc[0]  = fmaf(xv, w0.x,  acc[0]);
      acc[1]  = fmaf(xv, w0.y,  acc[1]);
      acc[2]  = fmaf(xv, w0.z,  acc[2]);
      acc[3]  = fmaf(xv, w0.w,  acc[3]);
      acc[4]  = fmaf(xv, w1.x,  acc[4]);
      acc[5]  = fmaf(xv, w1.y,  acc[5]);
      acc[6]  = fmaf(xv, w1.z,  acc[6]);
      acc[7]  = fmaf(xv, w1.w,  acc[7]);
      acc[8]  = fmaf(xv, w2v.x, acc[8]);
      acc[9]  = fmaf(xv, w2v.y, acc[9]);
      acc[10] = fmaf(xv, w2v.z, acc[10]);
      acc[11] = fmaf(xv, w2v.w, acc[11]);
      acc[12] = fmaf(xv, w3.x,  acc[12]);
      acc[13] = fmaf(xv, w3.y,  acc[13]);
      acc[14] = fmaf(xv, w3.z,  acc[14]);
      acc[15] = fmaf(xv, w3.w,  acc[15]);
    }

#pragma unroll
    for (int j = 0; j < 16; ++j) {
      float s = fmaf(-2.0f, acc[j], w2f[k0 + j]);
      bool lt = s < m1;
      float om1 = m1;
      m2 = lt ? om1 : fminf(s, m2);
      m1 = lt ? s : m1;
      i1 = lt ? (k0 + j) : i1;
    }
  }

  sm1[wid][lane] = m1;
  sm2[wid][lane] = m2;
  si1[wid][lane] = i1;
  __syncthreads();

  // ---- merge 4 waves (top-2); flag near-ties via ballot (wave 0) ----
  if (tid < 64) {
    float M1 = sm1[0][lane], M2 = sm2[0][lane];
    int   I1 = si1[0][lane];
#pragma unroll
    for (int c = 1; c < 4; ++c) {
      float c1 = sm1[c][lane];
      if (c1 < M1) { M2 = fminf(M1, sm2[c][lane]); M1 = c1; I1 = si1[c][lane]; }
      else         { M2 = fminf(M2, c1); }
    }
    skm[lane] = I1;
    unsigned long long bal = __ballot(M2 - M1 < FLAG_GAP);
    if (lane == 0) s_fmask = bal;
  }
  __syncthreads();

  // ---- bit-exact numpy-emulation fixup for flagged pixels (R7-proven) ----
  unsigned long long fm = s_fmask;
  while (fm) {
    const int L = __builtin_ctzll(fm);
    fm &= (fm - 1);
    const float x2L = sx2[L];
    float bv = 3.4e38f;
    int   bi = 0;
#pragma unroll
    for (int kk = 0; kk < 2; ++kk) {
      int k = tid + kk * 256;            // ascending: strict < keeps lowest k
      float dot = 0.0f;
      for (int d = 0; d < DDIM; ++d) {
        float p = xs[d][L] * w[d * KCODES + k];   // rounded product
        dot = dot + p;                            // rounded add, d ascending
      }
      float t  = x2L - 2.0f * dot;       // rounds at ulp(~64) — the ref's grid
      float s2 = t + w2f[k];             // rounds
      if (s2 < bv) { bv = s2; bi = k; }
    }
    rv[tid] = bv;
    ri[tid] = bi;
    __syncthreads();
    for (int off = 128; off > 0; off >>= 1) {
      if (tid < off) {
        float ov = rv[tid + off];
        int   oi = ri[tid + off];
        if (ov < rv[tid] || (ov == rv[tid] && oi < ri[tid])) {
          rv[tid] = ov;
          ri[tid] = oi;
        }
      }
      __syncthreads();
    }
    if (tid == 0) skm[L] = ri[0];
    __syncthreads();
  }

  // ---- outputs ----
  if (tid < 64) aout[pixbase + lane] = (float)skm[lane];

  const int kmin = skm[lane];
  float* qp = qout + (size_t)b * (DDIM * NPIX) + n0 + lane;
#pragma unroll
  for (int dd = 0; dd < 16; ++dd) {
    int d = wid * 16 + dd;
    qp[(size_t)d * NPIX] = w[d * KCODES + kmin];
  }
}

extern "C" void kernel_launch(void* const* d_in, const int* in_sizes, int n_in,
                              void* d_out, int out_size, void* d_ws, size_t ws_size,
                              hipStream_t stream) {
  const float* x = (const float*)d_in[0];
  const float* w = (const float*)d_in[1];
  float* qout = (float*)d_out;
  float* aout = (float*)d_out + QELEMS;

  vq_kernel<<<64 * 16, 256, 0, stream>>>(x, w, qout, aout);
}

// Round 9
// 60.407 us; speedup vs baseline: 3.1000x; 1.8117x over previous
//
#include <hip/hip_runtime.h>

#define KCODES 512
#define DDIM   64
#define NPIX   1024                      // 32*32 spatial per batch
#define QELEMS (64 * DDIM * NPIX)        // 4194304
// MFMA-path error <= ~4e-5 per s, 8e-5 per pair; ref-grid reorder <= 3.05e-5.
#define FLAG_GAP 1.5e-4f

typedef float f32x4 __attribute__((ext_vector_type(4)));
typedef short bf16x8 __attribute__((ext_vector_type(8)));
typedef unsigned int u32;
typedef u32 u32x4 __attribute__((ext_vector_type(4)));

// Pack 8 fp32 -> 8 bf16 (truncation) fragment; elem j = k-offset j.
__device__ __forceinline__ bf16x8 pack_hi(const float* f) {
  u32x4 wds;
#pragma unroll
  for (int p = 0; p < 4; ++p) {
    u32 u0 = __float_as_uint(f[2 * p]);
    u32 u1 = __float_as_uint(f[2 * p + 1]);
    wds[p] = (u0 >> 16) | (u1 & 0xffff0000u);
  }
  return __builtin_bit_cast(bf16x8, wds);
}
// Residual lo: bf16_trunc(f - upconvert(bf16_trunc(f))).
__device__ __forceinline__ bf16x8 pack_lo(const float* f) {
  u32x4 wds;
#pragma unroll
  for (int p = 0; p < 4; ++p) {
    float r0 = f[2 * p]     - __uint_as_float(__float_as_uint(f[2 * p])     & 0xffff0000u);
    float r1 = f[2 * p + 1] - __uint_as_float(__float_as_uint(f[2 * p + 1]) & 0xffff0000u);
    wds[p] = (__float_as_uint(r0) >> 16) | (__float_as_uint(r1) & 0xffff0000u);
  }
  return __builtin_bit_cast(bf16x8, wds);
}

// Main scan on matrix cores: s_k = w2_k - 2*dot_k, dot via split-bf16 MFMA
// (x_hi*w_hi + x_hi*w_lo + x_lo*w_hi, fp32 accum). Near-ties re-resolved with
// the BIT-EXACT numpy fp32 emulation (R3/R7-proven: seq d, separate mul+add,
// dist=(x2-2dot)+w2, strict-< first-min). w2/x2 always numpy-exact.
__global__ __launch_bounds__(256) void vq_kernel(
    const float* __restrict__ x, const float* __restrict__ w,
    float* __restrict__ qout, float* __restrict__ aout) {
#pragma clang fp contract(off)

  __shared__ float  xs[DDIM][65];        // padded: bank-friendly column reads
  __shared__ float  sx2[64];             // numpy-exact x2 per pixel
  __shared__ float  w2f[KCODES];         // numpy-exact ||w_k||^2
  __shared__ float  sm1[4][64], sm2[4][64];
  __shared__ int    si1[4][64];
  __shared__ int    skm[64];
  __shared__ unsigned long long s_fmask;
  __shared__ float  rv[256];
  __shared__ int    ri[256];

  const int tid  = threadIdx.x;
  const int lane = tid & 63;
  const int lr   = lane & 15;            // pixel-col / code-row within 16
  const int lg   = lane >> 4;            // k-group 0..3
  const int wid  = __builtin_amdgcn_readfirstlane(tid >> 6);
  const int b    = blockIdx.x >> 4;
  const int n0   = (blockIdx.x & 15) << 6;
  const size_t pixbase = (size_t)blockIdx.x << 6;

  // ---- stage x tile into LDS (coalesced 64-lane rows) ----
  {
    const float* xp = x + (size_t)b * (DDIM * NPIX) + n0;
#pragma unroll
    for (int dd = 0; dd < 16; ++dd) {
      int d = dd * 4 + wid;
      xs[d][lane] = xp[(size_t)d * NPIX + lane];
    }
  }

  // ---- w2 in fp32, sequential over d (numpy order), per block ----
#pragma unroll
  for (int kk = 0; kk < 2; ++kk) {
    int k = tid + kk * 256;
    float s = 0.0f;
    for (int d = 0; d < DDIM; ++d) {
      float v = w[d * KCODES + k];
      float p = v * v;
      s = s + p;
    }
    w2f[k] = s;
  }
  __syncthreads();

  // ---- numpy-exact x2 per pixel; wave 0 publishes ----
  {
    float x2 = 0.0f;
#pragma unroll
    for (int d = 0; d < DDIM; ++d) {
      float xv = xs[d][lane];
      float p = xv * xv;
      x2 = x2 + p;
    }
    if (tid < 64) sx2[lane] = x2;
  }

  // ---- build x (B) fragments: pixel n = pg*16+lr, k = lg*8+j+32h -> d ----
  bf16x8 bxh[4][2], bxl[4][2];
#pragma unroll
  for (int pg = 0; pg < 4; ++pg) {
#pragma unroll
    for (int h = 0; h < 2; ++h) {
      float f[8];
#pragma unroll
      for (int j = 0; j < 8; ++j)
        f[j] = xs[lg * 8 + j + 32 * h][pg * 16 + lr];
      bxh[pg][h] = pack_hi(f);
      bxl[pg][h] = pack_lo(f);
    }
  }

  // ---- MFMA scan: wave wid owns codes [wid*128, wid*128+128) ----
  float m1a[4], m2a[4];
  int   i1a[4];
#pragma unroll
  for (int pg = 0; pg < 4; ++pg) { m1a[pg] = 3.4e38f; m2a[pg] = 3.4e38f; i1a[pg] = 0; }

  float fw[2][8];                        // w column prefetch (code = base+lr)
  {
    const int mycode = wid * 128 + lr;
#pragma unroll
    for (int h = 0; h < 2; ++h)
#pragma unroll
      for (int j = 0; j < 8; ++j)
        fw[h][j] = w[(lg * 8 + j + 32 * h) * KCODES + mycode];
  }

#pragma unroll 1
  for (int cg = 0; cg < 8; ++cg) {
    const int codebase = wid * 128 + cg * 16;
    bf16x8 awh0 = pack_hi(fw[0]);
    bf16x8 awh1 = pack_hi(fw[1]);
    bf16x8 awl0 = pack_lo(fw[0]);
    bf16x8 awl1 = pack_lo(fw[1]);
    if (cg < 7) {                        // prefetch next code-group
      const int mycode = codebase + 16 + lr;
#pragma unroll
      for (int h = 0; h < 2; ++h)
#pragma unroll
        for (int j = 0; j < 8; ++j)
          fw[h][j] = w[(lg * 8 + j + 32 * h) * KCODES + mycode];
    }

#pragma unroll
    for (int pg = 0; pg < 4; ++pg) {
      f32x4 acc = {0.f, 0.f, 0.f, 0.f};
      acc = __builtin_amdgcn_mfma_f32_16x16x32_bf16(awh0, bxh[pg][0], acc, 0, 0, 0);
      acc = __builtin_amdgcn_mfma_f32_16x16x32_bf16(awh1, bxh[pg][1], acc, 0, 0, 0);
      acc = __builtin_amdgcn_mfma_f32_16x16x32_bf16(awl0, bxh[pg][0], acc, 0, 0, 0);
      acc = __builtin_amdgcn_mfma_f32_16x16x32_bf16(awl1, bxh[pg][1], acc, 0, 0, 0);
      acc = __builtin_amdgcn_mfma_f32_16x16x32_bf16(awh0, bxl[pg][0], acc, 0, 0, 0);
      acc = __builtin_amdgcn_mfma_f32_16x16x32_bf16(awh1, bxl[pg][1], acc, 0, 0, 0);
#pragma unroll
      for (int r = 0; r < 4; ++r) {      // C: row(code)=lg*4+r, col(pixel)=lr
        int code = codebase + lg * 4 + r;
        float s = w2f[code] - 2.0f * acc[r];
        bool lt = s < m1a[pg];
        float om1 = m1a[pg];
        m2a[pg] = lt ? om1 : fminf(s, m2a[pg]);
        m1a[pg] = lt ? s : m1a[pg];
        i1a[pg] = lt ? code : i1a[pg];
      }
    }
  }

  // ---- cross-lane top-2 merge over the 4 k-groups (lanes p,p+16,p+32,p+48) ----
#pragma unroll
  for (int pg = 0; pg < 4; ++pg) {
#pragma unroll
    for (int mi = 0; mi < 2; ++mi) {
      int mask = mi ? 32 : 16;
      float pm1 = __shfl_xor(m1a[pg], mask);
      float pm2 = __shfl_xor(m2a[pg], mask);
      int   pi1 = __shfl_xor(i1a[pg], mask);
      if (pm1 < m1a[pg]) { m2a[pg] = fminf(m1a[pg], pm2); m1a[pg] = pm1; i1a[pg] = pi1; }
      else               { m2a[pg] = fminf(m2a[pg], pm1); }
    }
  }
  if (lg == 0) {
#pragma unroll
    for (int pg = 0; pg < 4; ++pg) {
      sm1[wid][pg * 16 + lr] = m1a[pg];
      sm2[wid][pg * 16 + lr] = m2a[pg];
      si1[wid][pg * 16 + lr] = i1a[pg];
    }
  }
  __syncthreads();

  // ---- merge 4 waves (top-2); flag near-ties via ballot (wave 0) ----
  if (tid < 64) {
    float M1 = sm1[0][lane], M2 = sm2[0][lane];
    int   I1 = si1[0][lane];
#pragma unroll
    for (int c = 1; c < 4; ++c) {
      float c1 = sm1[c][lane];
      if (c1 < M1) { M2 = fminf(M1, sm2[c][lane]); M1 = c1; I1 = si1[c][lane]; }
      else         { M2 = fminf(M2, c1); }
    }
    skm[lane] = I1;
    unsigned long long bal = __ballot(M2 - M1 < FLAG_GAP);
    if (lane == 0) s_fmask = bal;
  }
  __syncthreads();

  // ---- bit-exact numpy-emulation fixup for flagged pixels (R7-proven) ----
  unsigned long long fm = s_fmask;
  while (fm) {
    const int L = __builtin_ctzll(fm);
    fm &= (fm - 1);
    const float x2L = sx2[L];
    float bv = 3.4e38f;
    int   bi = 0;
#pragma unroll
    for (int kk = 0; kk < 2; ++kk) {
      int k = tid + kk * 256;            // ascending: strict < keeps lowest k
      float dot = 0.0f;
      for (int d = 0; d < DDIM; ++d) {
        float p = xs[d][L] * w[d * KCODES + k];
        dot = dot + p;
      }
      float t  = x2L - 2.0f * dot;
      float s2 = t + w2f[k];
      if (s2 < bv) { bv = s2; bi = k; }
    }
    rv[tid] = bv;
    ri[tid] = bi;
    __syncthreads();
    for (int off = 128; off > 0; off >>= 1) {
      if (tid < off) {
        float ov = rv[tid + off];
        int   oi = ri[tid + off];
        if (ov < rv[tid] || (ov == rv[tid] && oi < ri[tid])) {
          rv[tid] = ov;
          ri[tid] = oi;
        }
      }
      __syncthreads();
    }
    if (tid == 0) skm[L] = ri[0];
    __syncthreads();
  }

  // ---- outputs ----
  if (tid < 64) aout[pixbase + lane] = (float)skm[lane];

  const int kmin = skm[lane];
  float* qp = qout + (size_t)b * (DDIM * NPIX) + n0 + lane;
#pragma unroll
  for (int dd = 0; dd < 16; ++dd) {
    int d = wid * 16 + dd;
    qp[(size_t)d * NPIX] = w[d * KCODES + kmin];
  }
}

extern "C" void kernel_launch(void* const* d_in, const int* in_sizes, int n_in,
                              void* d_out, int out_size, void* d_ws, size_t ws_size,
                              hipStream_t stream) {
  const float* x = (const float*)d_in[0];
  const float* w = (const float*)d_in[1];
  float* qout = (float*)d_out;
  float* aout = (float*)d_out + QELEMS;

  vq_kernel<<<64 * 16, 256, 0, stream>>>(x, w, qout, aout);
}

// Round 10
// 55.849 us; speedup vs baseline: 3.3530x; 1.0816x over previous
//
#include <hip/hip_runtime.h>

#define KCODES 512
#define DDIM   64
#define NPIX   1024                      // 32*32 spatial per batch
#define QELEMS (64 * DDIM * NPIX)        // 4194304
// MFMA-path error <= ~4e-5 per s, 8e-5 per pair; ref-grid reorder <= 3.05e-5.
#define FLAG_GAP 1.5e-4f

typedef float f32x4 __attribute__((ext_vector_type(4)));
typedef short bf16x8 __attribute__((ext_vector_type(8)));
typedef unsigned int u32;
typedef u32 u32x4 __attribute__((ext_vector_type(4)));

// ws layout: [0,2048) = f32 w2f[512]; [4096, 4096+131072) = packed A-frags
//   frag[(cg*4 + t)*64 + lane], t: 0=h0-hi 1=h1-hi 2=h0-lo 3=h1-lo, 16B each.

__device__ __forceinline__ bf16x8 pack_hi(const float* f) {
  u32x4 wds;
#pragma unroll
  for (int p = 0; p < 4; ++p) {
    u32 u0 = __float_as_uint(f[2 * p]);
    u32 u1 = __float_as_uint(f[2 * p + 1]);
    wds[p] = (u0 >> 16) | (u1 & 0xffff0000u);
  }
  return __builtin_bit_cast(bf16x8, wds);
}
__device__ __forceinline__ bf16x8 pack_lo(const float* f) {
  u32x4 wds;
#pragma unroll
  for (int p = 0; p < 4; ++p) {
    float r0 = f[2 * p]     - __uint_as_float(__float_as_uint(f[2 * p])     & 0xffff0000u);
    float r1 = f[2 * p + 1] - __uint_as_float(__float_as_uint(f[2 * p + 1]) & 0xffff0000u);
    wds[p] = (__float_as_uint(r0) >> 16) | (__float_as_uint(r1) & 0xffff0000u);
  }
  return __builtin_bit_cast(bf16x8, wds);
}

// One-time w-side prep: blocks 0..31 pack fragments; block 32 computes w2f.
__global__ void vq_prep(const float* __restrict__ w,
                        float* __restrict__ w2f_g,
                        bf16x8* __restrict__ frag) {
#pragma clang fp contract(off)
  const int blk = blockIdx.x;
  if (blk == 32) {
    int k = threadIdx.x;                 // 512 threads
    if (k < KCODES) {
      float s = 0.0f;
      for (int d = 0; d < DDIM; ++d) {
        float v = w[d * KCODES + k];
        float p = v * v;                 // rounded product
        s = s + p;                       // rounded add, d ascending (numpy)
      }
      w2f_g[k] = s;
    }
    return;
  }
  if (threadIdx.x >= 256) return;
  const int cg   = blk;                  // code-group 0..31
  const int t    = threadIdx.x >> 6;     // term 0..3
  const int lane = threadIdx.x & 63;
  const int code = cg * 16 + (lane & 15);
  const int h    = t & 1;
  float f[8];
#pragma unroll
  for (int j = 0; j < 8; ++j)
    f[j] = w[(h * 32 + (lane >> 4) * 8 + j) * KCODES + code];
  frag[(cg * 4 + t) * 64 + lane] = (t < 2) ? pack_hi(f) : pack_lo(f);
}

// Main scan on matrix cores: s_k = w2_k - 2*dot_k, dot via split-bf16 MFMA
// (x_hi*w_hi + x_hi*w_lo + x_lo*w_hi, fp32 accum), w prepacked in ws.
// Near-ties re-resolved with the BIT-EXACT numpy fp32 emulation (R3/R7-proven).
__global__ __launch_bounds__(256) void vq_kernel(
    const float* __restrict__ x, const float* __restrict__ w,
    const float* __restrict__ w2f_g, const bf16x8* __restrict__ frag,
    float* __restrict__ qout, float* __restrict__ aout) {
#pragma clang fp contract(off)

  __shared__ float  xs[DDIM][65];
  __shared__ float  sx2[64];
  __shared__ float  w2fs[KCODES];
  __shared__ float  sm1[4][64], sm2[4][64];
  __shared__ int    si1[4][64];
  __shared__ int    skm[64];
  __shared__ unsigned long long s_fmask;
  __shared__ float  rv[256];
  __shared__ int    ri[256];

  const int tid  = threadIdx.x;
  const int lane = tid & 63;
  const int lr   = lane & 15;            // pixel-col / code-row within 16
  const int lg   = lane >> 4;            // group 0..3
  const int wid  = __builtin_amdgcn_readfirstlane(tid >> 6);
  const int b    = blockIdx.x >> 4;
  const int n0   = (blockIdx.x & 15) << 6;
  const size_t pixbase = (size_t)blockIdx.x << 6;

  // ---- stage x tile into LDS; load w2f from ws (both coalesced) ----
  {
    const float* xp = x + (size_t)b * (DDIM * NPIX) + n0;
#pragma unroll
    for (int dd = 0; dd < 16; ++dd) {
      int d = dd * 4 + wid;
      xs[d][lane] = xp[(size_t)d * NPIX + lane];
    }
  }
  w2fs[tid]       = w2f_g[tid];
  w2fs[tid + 256] = w2f_g[tid + 256];
  __syncthreads();

  // ---- numpy-exact x2 per pixel; wave 0 publishes ----
  {
    float x2 = 0.0f;
#pragma unroll
    for (int d = 0; d < DDIM; ++d) {
      float xv = xs[d][lane];
      float p = xv * xv;
      x2 = x2 + p;
    }
    if (tid < 64) sx2[lane] = x2;
  }

  // ---- build x (B) fragments: pixel n = pg*16+lr, k-elem j -> d ----
  bf16x8 bxh[4][2], bxl[4][2];
#pragma unroll
  for (int pg = 0; pg < 4; ++pg) {
#pragma unroll
    for (int h = 0; h < 2; ++h) {
      float f[8];
#pragma unroll
      for (int j = 0; j < 8; ++j)
        f[j] = xs[h * 32 + lg * 8 + j][pg * 16 + lr];
      bxh[pg][h] = pack_hi(f);
      bxl[pg][h] = pack_lo(f);
    }
  }

  // ---- MFMA scan: wave wid owns codes [wid*128, wid*128+128) ----
  float m1a[4], m2a[4];
  int   i1a[4];
#pragma unroll
  for (int pg = 0; pg < 4; ++pg) { m1a[pg] = 3.4e38f; m2a[pg] = 3.4e38f; i1a[pg] = 0; }

#pragma unroll
  for (int cg = 0; cg < 8; ++cg) {
    const int codebase = wid * 128 + cg * 16;
    const bf16x8* fr = frag + (size_t)(wid * 8 + cg) * 4 * 64 + lane;
    bf16x8 awh0 = fr[0];                 // coalesced dwordx4, L2-resident
    bf16x8 awh1 = fr[64];
    bf16x8 awl0 = fr[128];
    bf16x8 awl1 = fr[192];

#pragma unroll
    for (int pg = 0; pg < 4; ++pg) {
      f32x4 acc = {0.f, 0.f, 0.f, 0.f};
      acc = __builtin_amdgcn_mfma_f32_16x16x32_bf16(awh0, bxh[pg][0], acc, 0, 0, 0);
      acc = __builtin_amdgcn_mfma_f32_16x16x32_bf16(awh1, bxh[pg][1], acc, 0, 0, 0);
      acc = __builtin_amdgcn_mfma_f32_16x16x32_bf16(awl0, bxh[pg][0], acc, 0, 0, 0);
      acc = __builtin_amdgcn_mfma_f32_16x16x32_bf16(awl1, bxh[pg][1], acc, 0, 0, 0);
      acc = __builtin_amdgcn_mfma_f32_16x16x32_bf16(awh0, bxl[pg][0], acc, 0, 0, 0);
      acc = __builtin_amdgcn_mfma_f32_16x16x32_bf16(awh1, bxl[pg][1], acc, 0, 0, 0);
#pragma unroll
      for (int r = 0; r < 4; ++r) {      // C: row(code)=lg*4+r, col(pixel)=lr
        int code = codebase + lg * 4 + r;
        float s = w2fs[code] - 2.0f * acc[r];
        bool lt = s < m1a[pg];
        float om1 = m1a[pg];
        m2a[pg] = lt ? om1 : fminf(s, m2a[pg]);
        m1a[pg] = lt ? s : m1a[pg];
        i1a[pg] = lt ? code : i1a[pg];
      }
    }
  }

  // ---- cross-lane top-2 merge over the 4 lg groups ----
#pragma unroll
  for (int pg = 0; pg < 4; ++pg) {
#pragma unroll
    for (int mi = 0; mi < 2; ++mi) {
      int mask = mi ? 32 : 16;
      float pm1 = __shfl_xor(m1a[pg], mask);
      float pm2 = __shfl_xor(m2a[pg], mask);
      int   pi1 = __shfl_xor(i1a[pg], mask);
      if (pm1 < m1a[pg]) { m2a[pg] = fminf(m1a[pg], pm2); m1a[pg] = pm1; i1a[pg] = pi1; }
      else               { m2a[pg] = fminf(m2a[pg], pm1); }
    }
  }
  if (lg == 0) {
#pragma unroll
    for (int pg = 0; pg < 4; ++pg) {
      sm1[wid][pg * 16 + lr] = m1a[pg];
      sm2[wid][pg * 16 + lr] = m2a[pg];
      si1[wid][pg * 16 + lr] = i1a[pg];
    }
  }
  __syncthreads();

  // ---- merge 4 waves (top-2); flag near-ties via ballot (wave 0) ----
  if (tid < 64) {
    float M1 = sm1[0][lane], M2 = sm2[0][lane];
    int   I1 = si1[0][lane];
#pragma unroll
    for (int c = 1; c < 4; ++c) {
      float c1 = sm1[c][lane];
      if (c1 < M1) { M2 = fminf(M1, sm2[c][lane]); M1 = c1; I1 = si1[c][lane]; }
      else         { M2 = fminf(M2, c1); }
    }
    skm[lane] = I1;
    unsigned long long bal = __ballot(M2 - M1 < FLAG_GAP);
    if (lane == 0) s_fmask = bal;
  }
  __syncthreads();

  // ---- bit-exact numpy-emulation fixup for flagged pixels (R7-proven) ----
  unsigned long long fm = s_fmask;
  while (fm) {
    const int L = __builtin_ctzll(fm);
    fm &= (fm - 1);
    const float x2L = sx2[L];
    float bv = 3.4e38f;
    int   bi = 0;
#pragma unroll
    for (int kk = 0; kk < 2; ++kk) {
      int k = tid + kk * 256;            // ascending: strict < keeps lowest k
      float dot = 0.0f;
      for (int d = 0; d < DDIM; ++d) {
        float p = xs[d][L] * w[d * KCODES + k];
        dot = dot + p;
      }
      float t  = x2L - 2.0f * dot;
      float s2 = t + w2fs[k];
      if (s2 < bv) { bv = s2; bi = k; }
    }
    rv[tid] = bv;
    ri[tid] = bi;
    __syncthreads();
    for (int off = 128; off > 0; off >>= 1) {
      if (tid < off) {
        float ov = rv[tid + off];
        int   oi = ri[tid + off];
        if (ov < rv[tid] || (ov == rv[tid] && oi < ri[tid])) {
          rv[tid] = ov;
          ri[tid] = oi;
        }
      }
      __syncthreads();
    }
    if (tid == 0) skm[L] = ri[0];
    __syncthreads();
  }

  // ---- outputs ----
  if (tid < 64) aout[pixbase + lane] = (float)skm[lane];

  const int kmin = skm[lane];
  float* qp = qout + (size_t)b * (DDIM * NPIX) + n0 + lane;
#pragma unroll
  for (int dd = 0; dd < 16; ++dd) {
    int d = wid * 16 + dd;
    qp[(size_t)d * NPIX] = w[d * KCODES + kmin];
  }
}

extern "C" void kernel_launch(void* const* d_in, const int* in_sizes, int n_in,
                              void* d_out, int out_size, void* d_ws, size_t ws_size,
                              hipStream_t stream) {
  const float* x = (const float*)d_in[0];
  const float* w = (const float*)d_in[1];
  float* qout = (float*)d_out;
  float* aout = (float*)d_out + QELEMS;

  char*   wsb   = (char*)d_ws;
  float*  w2f_g = (float*)wsb;                   // 2 KB
  bf16x8* frag  = (bf16x8*)(wsb + 4096);         // 128 KB

  vq_prep<<<33, 512, 0, stream>>>(w, w2f_g, frag);
  vq_kernel<<<64 * 16, 256, 0, stream>>>(x, w, w2f_g, frag, qout, aout);
}

// Round 11
// 48.622 us; speedup vs baseline: 3.8514x; 1.1486x over previous
//
#include <hip/hip_runtime.h>

#define KCODES 512
#define DDIM   64
#define NPIX   1024                      // 32*32 spatial per batch
#define QELEMS (64 * DDIM * NPIX)        // 4194304
// 4-term MFMA dot error < ~2e-6 per s; ref-grid reorder bound: 2 roundings
// at ulp(x2<256)/2 = 1.53e-5 each, 2 dists -> 6.1e-5. Flag at 8e-5.
#define FLAG_GAP 8e-5f

typedef float f32x4 __attribute__((ext_vector_type(4)));
typedef short bf16x8 __attribute__((ext_vector_type(8)));
typedef unsigned int u32;
typedef u32 u32x4 __attribute__((ext_vector_type(4)));

// ws layout: [0,2048) = f32 w2f[512]; [4096, 4096+131072) = packed A-frags
//   frag[(cg*4 + t)*64 + lane], t: 0=h0-hi 1=h1-hi 2=h0-lo 3=h1-lo, 16B each.

__device__ __forceinline__ bf16x8 pack_hi(const float* f) {
  u32x4 wds;
#pragma unroll
  for (int p = 0; p < 4; ++p) {
    u32 u0 = __float_as_uint(f[2 * p]);
    u32 u1 = __float_as_uint(f[2 * p + 1]);
    wds[p] = (u0 >> 16) | (u1 & 0xffff0000u);
  }
  return __builtin_bit_cast(bf16x8, wds);
}
__device__ __forceinline__ bf16x8 pack_lo(const float* f) {
  u32x4 wds;
#pragma unroll
  for (int p = 0; p < 4; ++p) {
    float r0 = f[2 * p]     - __uint_as_float(__float_as_uint(f[2 * p])     & 0xffff0000u);
    float r1 = f[2 * p + 1] - __uint_as_float(__float_as_uint(f[2 * p + 1]) & 0xffff0000u);
    wds[p] = (__float_as_uint(r0) >> 16) | (__float_as_uint(r1) & 0xffff0000u);
  }
  return __builtin_bit_cast(bf16x8, wds);
}

// One-time w-side prep: blocks 0..31 pack fragments; block 32 computes w2f.
__global__ void vq_prep(const float* __restrict__ w,
                        float* __restrict__ w2f_g,
                        bf16x8* __restrict__ frag) {
#pragma clang fp contract(off)
  const int blk = blockIdx.x;
  if (blk == 32) {
    int k = threadIdx.x;                 // 512 threads
    if (k < KCODES) {
      float s = 0.0f;
      for (int d = 0; d < DDIM; ++d) {
        float v = w[d * KCODES + k];
        float p = v * v;                 // rounded product
        s = s + p;                       // rounded add, d ascending (numpy)
      }
      w2f_g[k] = s;
    }
    return;
  }
  if (threadIdx.x >= 256) return;
  const int cg   = blk;                  // code-group 0..31
  const int t    = threadIdx.x >> 6;     // term 0..3
  const int lane = threadIdx.x & 63;
  const int code = cg * 16 + (lane & 15);
  const int h    = t & 1;
  float f[8];
#pragma unroll
  for (int j = 0; j < 8; ++j)
    f[j] = w[(h * 32 + (lane >> 4) * 8 + j) * KCODES + code];
  frag[(cg * 4 + t) * 64 + lane] = (t < 2) ? pack_hi(f) : pack_lo(f);
}

// Main scan on matrix cores: s_k = w2_k - 2*dot_k, dot via 4-term split-bf16
// MFMA (hh + hl + lh + ll, fp32 accum), w prepacked in ws. Near-ties
// re-resolved per-WAVE (barrier-free) with the BIT-EXACT numpy fp32 emulation
// (R3/R7-proven: seq d, separate mul+add, (x2-2dot)+w2, strict-< first-min).
__global__ __launch_bounds__(256) void vq_kernel(
    const float* __restrict__ x, const float* __restrict__ w,
    const float* __restrict__ w2f_g, const bf16x8* __restrict__ frag,
    float* __restrict__ qout, float* __restrict__ aout) {
#pragma clang fp contract(off)

  __shared__ float  xs[DDIM][65];
  __shared__ float  sx2[64];
  __shared__ float  w2fs[KCODES];
  __shared__ float  sm1[4][64], sm2[4][64];
  __shared__ int    si1[4][64];
  __shared__ int    skm[64];
  __shared__ unsigned long long s_fmask;

  const int tid  = threadIdx.x;
  const int lane = tid & 63;
  const int lr   = lane & 15;            // pixel-col / code-row within 16
  const int lg   = lane >> 4;            // group 0..3
  const int wid  = __builtin_amdgcn_readfirstlane(tid >> 6);
  const int b    = blockIdx.x >> 4;
  const int n0   = (blockIdx.x & 15) << 6;
  const size_t pixbase = (size_t)blockIdx.x << 6;

  // ---- stage x tile into LDS; load w2f from ws (both coalesced) ----
  {
    const float* xp = x + (size_t)b * (DDIM * NPIX) + n0;
#pragma unroll
    for (int dd = 0; dd < 16; ++dd) {
      int d = dd * 4 + wid;
      xs[d][lane] = xp[(size_t)d * NPIX + lane];
    }
  }
  w2fs[tid]       = w2f_g[tid];
  w2fs[tid + 256] = w2f_g[tid + 256];
  __syncthreads();

  // ---- numpy-exact x2 per pixel; wave 0 publishes ----
  {
    float x2 = 0.0f;
#pragma unroll
    for (int d = 0; d < DDIM; ++d) {
      float xv = xs[d][lane];
      float p = xv * xv;
      x2 = x2 + p;
    }
    if (tid < 64) sx2[lane] = x2;
  }

  // ---- build x (B) fragments: pixel n = pg*16+lr, k-elem j -> d ----
  bf16x8 bxh[4][2], bxl[4][2];
#pragma unroll
  for (int pg = 0; pg < 4; ++pg) {
#pragma unroll
    for (int h = 0; h < 2; ++h) {
      float f[8];
#pragma unroll
      for (int j = 0; j < 8; ++j)
        f[j] = xs[h * 32 + lg * 8 + j][pg * 16 + lr];
      bxh[pg][h] = pack_hi(f);
      bxl[pg][h] = pack_lo(f);
    }
  }

  // ---- MFMA scan: wave wid owns codes [wid*128, wid*128+128) ----
  float m1a[4], m2a[4];
  int   i1a[4];
#pragma unroll
  for (int pg = 0; pg < 4; ++pg) { m1a[pg] = 3.4e38f; m2a[pg] = 3.4e38f; i1a[pg] = 0; }

#pragma unroll
  for (int cg = 0; cg < 8; ++cg) {
    const int codebase = wid * 128 + cg * 16;
    const bf16x8* fr = frag + (size_t)(wid * 8 + cg) * 4 * 64 + lane;
    bf16x8 awh0 = fr[0];                 // coalesced dwordx4, L2-resident
    bf16x8 awh1 = fr[64];
    bf16x8 awl0 = fr[128];
    bf16x8 awl1 = fr[192];

#pragma unroll
    for (int pg = 0; pg < 4; ++pg) {
      f32x4 acc = {0.f, 0.f, 0.f, 0.f};
      acc = __builtin_amdgcn_mfma_f32_16x16x32_bf16(awh0, bxh[pg][0], acc, 0, 0, 0);
      acc = __builtin_amdgcn_mfma_f32_16x16x32_bf16(awh1, bxh[pg][1], acc, 0, 0, 0);
      acc = __builtin_amdgcn_mfma_f32_16x16x32_bf16(awl0, bxh[pg][0], acc, 0, 0, 0);
      acc = __builtin_amdgcn_mfma_f32_16x16x32_bf16(awl1, bxh[pg][1], acc, 0, 0, 0);
      acc = __builtin_amdgcn_mfma_f32_16x16x32_bf16(awh0, bxl[pg][0], acc, 0, 0, 0);
      acc = __builtin_amdgcn_mfma_f32_16x16x32_bf16(awh1, bxl[pg][1], acc, 0, 0, 0);
      acc = __builtin_amdgcn_mfma_f32_16x16x32_bf16(awl0, bxl[pg][0], acc, 0, 0, 0);
      acc = __builtin_amdgcn_mfma_f32_16x16x32_bf16(awl1, bxl[pg][1], acc, 0, 0, 0);
#pragma unroll
      for (int r = 0; r < 4; ++r) {      // C: row(code)=lg*4+r, col(pixel)=lr
        int code = codebase + lg * 4 + r;
        float s = w2fs[code] - 2.0f * acc[r];
        bool lt = s < m1a[pg];
        float om1 = m1a[pg];
        m2a[pg] = lt ? om1 : fminf(s, m2a[pg]);
        m1a[pg] = lt ? s : m1a[pg];
        i1a[pg] = lt ? code : i1a[pg];
      }
    }
  }

  // ---- cross-lane top-2 merge over the 4 lg groups ----
#pragma unroll
  for (int pg = 0; pg < 4; ++pg) {
#pragma unroll
    for (int mi = 0; mi < 2; ++mi) {
      int mask = mi ? 32 : 16;
      float pm1 = __shfl_xor(m1a[pg], mask);
      float pm2 = __shfl_xor(m2a[pg], mask);
      int   pi1 = __shfl_xor(i1a[pg], mask);
      if (pm1 < m1a[pg]) { m2a[pg] = fminf(m1a[pg], pm2); m1a[pg] = pm1; i1a[pg] = pi1; }
      else               { m2a[pg] = fminf(m2a[pg], pm1); }
    }
  }
  if (lg == 0) {
#pragma unroll
    for (int pg = 0; pg < 4; ++pg) {
      sm1[wid][pg * 16 + lr] = m1a[pg];
      sm2[wid][pg * 16 + lr] = m2a[pg];
      si1[wid][pg * 16 + lr] = i1a[pg];
    }
  }
  __syncthreads();

  // ---- merge 4 waves (top-2); flag near-ties via ballot (wave 0) ----
  if (tid < 64) {
    float M1 = sm1[0][lane], M2 = sm2[0][lane];
    int   I1 = si1[0][lane];
#pragma unroll
    for (int c = 1; c < 4; ++c) {
      float c1 = sm1[c][lane];
      if (c1 < M1) { M2 = fminf(M1, sm2[c][lane]); M1 = c1; I1 = si1[c][lane]; }
      else         { M2 = fminf(M2, c1); }
    }
    skm[lane] = I1;
    unsigned long long bal = __ballot(M2 - M1 < FLAG_GAP);
    if (lane == 0) s_fmask = bal;
  }
  __syncthreads();

  // ---- bit-exact numpy-emulation fixup, wave-local (no barriers) ----
  {
    unsigned long long fm = s_fmask;
    int idx = 0;
    while (fm) {
      const int L = __builtin_ctzll(fm);
      fm &= (fm - 1);
      if ((idx++ & 3) != wid) continue;  // round-robin flagged pixels to waves
      const float x2L = sx2[L];
      const int k0 = lane * 8;           // lane covers codes [k0, k0+8)
      float dots[8];
#pragma unroll
      for (int c = 0; c < 8; ++c) dots[c] = 0.f;
      for (int d = 0; d < DDIM; ++d) {
        float xv = xs[d][L];
        const float* wr = w + d * KCODES + k0;
#pragma unroll
        for (int c = 0; c < 8; ++c) {
          float p = xv * wr[c];          // rounded product
          dots[c] = dots[c] + p;         // rounded add, d ascending (numpy)
        }
      }
      float bv = 3.4e38f;
      int   bi = 0;
#pragma unroll
      for (int c = 0; c < 8; ++c) {      // ascending c: strict < keeps lowest k
        float t  = x2L - 2.0f * dots[c];
        float s2 = t + w2fs[k0 + c];
        if (s2 < bv) { bv = s2; bi = k0 + c; }
      }
#pragma unroll
      for (int off = 1; off < 64; off <<= 1) {   // lexicographic min all-reduce
        float ov = __shfl_xor(bv, off);
        int   oi = __shfl_xor(bi, off);
        if (ov < bv || (ov == bv && oi < bi)) { bv = ov; bi = oi; }
      }
      if (lane == 0) skm[L] = bi;
    }
  }
  __syncthreads();

  // ---- outputs ----
  if (tid < 64) aout[pixbase + lane] = (float)skm[lane];

  const int kmin = skm[lane];
  float* qp = qout + (size_t)b * (DDIM * NPIX) + n0 + lane;
#pragma unroll
  for (int dd = 0; dd < 16; ++dd) {
    int d = wid * 16 + dd;
    qp[(size_t)d * NPIX] = w[d * KCODES + kmin];
  }
}

extern "C" void kernel_launch(void* const* d_in, const int* in_sizes, int n_in,
                              void* d_out, int out_size, void* d_ws, size_t ws_size,
                              hipStream_t stream) {
  const float* x = (const float*)d_in[0];
  const float* w = (const float*)d_in[1];
  float* qout = (float*)d_out;
  float* aout = (float*)d_out + QELEMS;

  char*   wsb   = (char*)d_ws;
  float*  w2f_g = (float*)wsb;                   // 2 KB
  bf16x8* frag  = (bf16x8*)(wsb + 4096);         // 128 KB

  vq_prep<<<33, 512, 0, stream>>>(w, w2f_g, frag);
  vq_kernel<<<64 * 16, 256, 0, stream>>>(x, w, w2f_g, frag, qout, aout);
}